// Round 8
// baseline (569.164 us; speedup 1.0000x reference)
//
#include <hip/hip_runtime.h>
#include <math.h>

#define N_ATOMS 100000
#define B_BB    10000
#define E_EDGES 320000
#define D_DIM   256
#define NHEAD   8
#define NDIST   64
#define EPAD    128

#define DELTA   (10.0f/63.0f)
#define GCOEFF  (-0.5f/(DELTA*DELTA))
#define QKSCALE 0.17677669529663687f   /* 1/sqrt(32) */

// ---------------------------------------------------------------------------
// K0: per-bb atom offsets via binary search (bb_vec sorted); zero edge_cnt
// ---------------------------------------------------------------------------
__global__ void k_offsets(const int* __restrict__ bb_vec, int* __restrict__ atom_off,
                          int* __restrict__ edge_cnt) {
  int b = blockIdx.x * 256 + threadIdx.x;
  if (b <= B_BB) {
    int lo = 0, hi = N_ATOMS;
    while (lo < hi) { int mid = (lo + hi) >> 1; if (bb_vec[mid] < b) lo = mid + 1; else hi = mid; }
    atom_off[b] = lo;
  }
  if (b < B_BB) edge_cnt[b] = 0;
}

// ---------------------------------------------------------------------------
// K1: bb_center_feats (sum) and bb_center_pos (mean). Grid-stride over bbs.
// ---------------------------------------------------------------------------
__global__ __launch_bounds__(256) void k_bb_centers(
    const float* __restrict__ af, const float* __restrict__ coords,
    const int* __restrict__ atom_off, float* __restrict__ bbF, float* __restrict__ bb_pos) {
  int t = threadIdx.x;
  for (int b = blockIdx.x; b < B_BB; b += gridDim.x) {
    int s = atom_off[b], e = atom_off[b + 1];
    float acc = 0.f;
    for (int a = s; a < e; a++) acc += af[(size_t)a * D_DIM + t];
    bbF[(size_t)b * D_DIM + t] = acc;
    if (t < 3) {
      float c = 0.f;
      for (int a = s; a < e; a++) c += coords[(size_t)a * 3 + t];
      float cnt = (float)(e - s);
      bb_pos[b * 4 + t] = c / fmaxf(cnt, 1.0f);
    }
  }
}

// ---------------------------------------------------------------------------
// K2/K9 v3: C[M,256] = A[M,256] @ W[256,256] + bias. 64x64 tile, 4x4 microtile
// + register-staged double buffer, one barrier per K-chunk (R6, ~-7us total).
// ---------------------------------------------------------------------------
__global__ __launch_bounds__(256) void k_gemm256(
    const float* __restrict__ A, const float* __restrict__ W,
    const float* __restrict__ bias, float* __restrict__ C, int M) {
  __shared__ __align__(16) float As[2][16][68];
  __shared__ __align__(16) float Ws[2][16][64];
  int tid = threadIdx.x;
  int tx = tid & 15, ty = tid >> 4;
  int row0 = blockIdx.x * 64, col0 = blockIdx.y * 64;
  int ar = tid >> 2, ac = (tid & 3) * 4;      // A stage: row ar, cols ac..ac+3
  int wr = tid >> 4, wc = (tid & 15) * 4;     // W stage: row wr, cols wc..wc+3
  int arow = row0 + ar;
  const float* Ap = A + (size_t)arow * 256 + ac;
  const float* Wp = W + (size_t)wr * 256 + col0 + wc;
  float acc[4][4] = {};
  {
    float4 va = make_float4(0.f, 0.f, 0.f, 0.f);
    if (arow < M) va = *(const float4*)Ap;
    As[0][ac + 0][ar] = va.x; As[0][ac + 1][ar] = va.y;
    As[0][ac + 2][ar] = va.z; As[0][ac + 3][ar] = va.w;
    *(float4*)&Ws[0][wr][wc] = *(const float4*)Wp;
  }
  __syncthreads();
  int cur = 0;
  for (int k0 = 0; k0 < 256; k0 += 16) {
    float4 va, vw;
    bool nxt = (k0 + 16) < 256;
    if (nxt) {
      va = make_float4(0.f, 0.f, 0.f, 0.f);
      if (arow < M) va = *(const float4*)(Ap + k0 + 16);
      vw = *(const float4*)(Wp + (size_t)(k0 + 16) * 256);
    }
#pragma unroll
    for (int kk = 0; kk < 16; kk++) {
      float4 a = *(const float4*)&As[cur][kk][ty * 4];
      float4 b = *(const float4*)&Ws[cur][kk][tx * 4];
      float av[4] = {a.x, a.y, a.z, a.w};
      float bv4[4] = {b.x, b.y, b.z, b.w};
#pragma unroll
      for (int i = 0; i < 4; i++)
#pragma unroll
        for (int j = 0; j < 4; j++) acc[i][j] += av[i] * bv4[j];
    }
    if (nxt) {
      As[cur ^ 1][ac + 0][ar] = va.x; As[cur ^ 1][ac + 1][ar] = va.y;
      As[cur ^ 1][ac + 2][ar] = va.z; As[cur ^ 1][ac + 3][ar] = va.w;
      *(float4*)&Ws[cur ^ 1][wr][wc] = vw;
      __syncthreads();
      cur ^= 1;
    }
  }
#pragma unroll
  for (int i = 0; i < 4; i++) {
    int row = row0 + ty * 4 + i;
    if (row < M) {
      int col = col0 + tx * 4;
      float4 r = make_float4(acc[i][0] + bias[col + 0], acc[i][1] + bias[col + 1],
                             acc[i][2] + bias[col + 2], acc[i][3] + bias[col + 3]);
      *(float4*)&C[(size_t)row * 256 + col] = r;
    }
  }
}

// ---------------------------------------------------------------------------
// K3: histogram of tgt
// ---------------------------------------------------------------------------
__global__ void k_hist(const int* __restrict__ tgt, int* __restrict__ edge_cnt) {
  int e = blockIdx.x * 256 + threadIdx.x;
  if (e < E_EDGES) atomicAdd(&edge_cnt[tgt[e]], 1);
}

// ---------------------------------------------------------------------------
// K4: exclusive scan of edge_cnt -> edge_start[B+1], cursor. Single block.
//     Also zero-fills the EPAD tail of src_sorted/dist_sorted.
// ---------------------------------------------------------------------------
__global__ __launch_bounds__(1024) void k_scan(
    const int* __restrict__ edge_cnt, int* __restrict__ edge_start, int* __restrict__ cursor,
    int* __restrict__ src_sorted, float* __restrict__ dist_sorted) {
  __shared__ int ssum[1024];
  int tid = threadIdx.x;
  int base = tid * 10;
  int v[10]; int s = 0;
#pragma unroll
  for (int k = 0; k < 10; k++) { int i = base + k; v[k] = (i < B_BB) ? edge_cnt[i] : 0; s += v[k]; }
  ssum[tid] = s;
  __syncthreads();
  for (int off = 1; off < 1024; off <<= 1) {
    int t = (tid >= off) ? ssum[tid - off] : 0;
    __syncthreads();
    ssum[tid] += t;
    __syncthreads();
  }
  int excl = ssum[tid] - s;
#pragma unroll
  for (int k = 0; k < 10; k++) {
    int i = base + k;
    if (i < B_BB) { edge_start[i] = excl; cursor[i] = excl; }
    excl += v[k];
  }
  if (tid == 1023) edge_start[B_BB] = E_EDGES;
  if (tid < EPAD) { src_sorted[E_EDGES + tid] = 0; dist_sorted[E_EDGES + tid] = 0.f; }
}

// ---------------------------------------------------------------------------
// K5: CSR fill: src_sorted / dist_sorted in tgt-grouped order
// ---------------------------------------------------------------------------
__global__ void k_fill(const int* __restrict__ src, const int* __restrict__ tgt,
                       const float* __restrict__ coords, const float* __restrict__ bb_pos,
                       int* __restrict__ cursor, int* __restrict__ src_sorted,
                       float* __restrict__ dist_sorted) {
  int e = blockIdx.x * 256 + threadIdx.x;
  if (e >= E_EDGES) return;
  int b = tgt[e], a = src[e];
  int pos = atomicAdd(&cursor[b], 1);
  float dx = coords[a * 3 + 0] - bb_pos[b * 4 + 0];
  float dy = coords[a * 3 + 1] - bb_pos[b * 4 + 1];
  float dz = coords[a * 3 + 2] - bb_pos[b * 4 + 2];
  src_sorted[pos] = a;
  dist_sorted[pos] = sqrtf(dx * dx + dy * dy + dz * dz);
}

// ---------------------------------------------------------------------------
// K6 v2: wt[b, h*320+i] = QKSCALE * sum_c q[b,h*32+c] * Wk[i, h*32+c]
// Register-blocked tile GEMM: 128 b-rows x 64 i-cols, K=32. grid (79,5,8).
// ---------------------------------------------------------------------------
__global__ __launch_bounds__(256) void k_wt(
    const float* __restrict__ q, const float* __restrict__ Wk, float* __restrict__ wt) {
  __shared__ __align__(16) float As[32][132];   // q transposed: As[c][row]
  __shared__ __align__(16) float Bs[32][68];    // Wk transposed: Bs[c][icol]
  int tid = threadIdx.x;
  int b0 = blockIdx.x * 128;
  int i0 = blockIdx.y * 64;
  int h  = blockIdx.z;
  {
    int r = tid >> 1, c0 = (tid & 1) * 16;
    int row = b0 + r;
    const float* qp = q + (size_t)row * 256 + h * 32 + c0;
#pragma unroll
    for (int jj = 0; jj < 4; ++jj) {
      float4 v = make_float4(0.f, 0.f, 0.f, 0.f);
      if (row < B_BB) v = *(const float4*)(qp + 4 * jj);
      As[c0 + 4*jj + 0][r] = v.x; As[c0 + 4*jj + 1][r] = v.y;
      As[c0 + 4*jj + 2][r] = v.z; As[c0 + 4*jj + 3][r] = v.w;
    }
  }
  {
    int r = tid >> 2, c0 = (tid & 3) * 8;
    const float* wp = Wk + (size_t)(i0 + r) * 256 + h * 32 + c0;
#pragma unroll
    for (int jj = 0; jj < 2; ++jj) {
      float4 v = *(const float4*)(wp + 4 * jj);
      Bs[c0 + 4*jj + 0][r] = v.x; Bs[c0 + 4*jj + 1][r] = v.y;
      Bs[c0 + 4*jj + 2][r] = v.z; Bs[c0 + 4*jj + 3][r] = v.w;
    }
  }
  __syncthreads();
  int tx = tid & 15, ty = tid >> 4;             // cols tx*4, rows ty*8
  float acc[8][4] = {};
#pragma unroll
  for (int kk = 0; kk < 32; ++kk) {
    float4 a0 = *(const float4*)&As[kk][ty * 8];
    float4 a1 = *(const float4*)&As[kk][ty * 8 + 4];
    float4 b4 = *(const float4*)&Bs[kk][tx * 4];
    float av[8] = {a0.x, a0.y, a0.z, a0.w, a1.x, a1.y, a1.z, a1.w};
    float bv4[4] = {b4.x, b4.y, b4.z, b4.w};
#pragma unroll
    for (int i = 0; i < 8; ++i)
#pragma unroll
      for (int j = 0; j < 4; ++j) acc[i][j] += av[i] * bv4[j];
  }
#pragma unroll
  for (int i = 0; i < 8; ++i) {
    int row = b0 + ty * 8 + i;
    if (row < B_BB) {
      float4 o = make_float4(acc[i][0] * QKSCALE, acc[i][1] * QKSCALE,
                             acc[i][2] * QKSCALE, acc[i][3] * QKSCALE);
      *(float4*)&wt[(size_t)row * 2560 + h * 320 + i0 + tx * 4] = o;
    }
  }
}

// ---------------------------------------------------------------------------
// K7 v10 (best: 157us): 8-edge iterations, two interleaved independent
// dot/shfl/exp chains; 1 bb per block. Reverted from BB_PER_BLK=4 (R7: +11us).
// k_attn has equilibrated at ~157us across 4 structural variants — frozen.
// ---------------------------------------------------------------------------
#define FMA4(p, v, Wb, k) \
  p = fmaf((v).x, Wb[(k)], p);   p = fmaf((v).y, Wb[(k)+1], p); \
  p = fmaf((v).z, Wb[(k)+2], p); p = fmaf((v).w, Wb[(k)+3], p);

#define ACC4(Sarr, k, ww, v) \
  Sarr[(k)]   = fmaf(ww, (v).x, Sarr[(k)]);   Sarr[(k)+1] = fmaf(ww, (v).y, Sarr[(k)+1]); \
  Sarr[(k)+2] = fmaf(ww, (v).z, Sarr[(k)+2]); Sarr[(k)+3] = fmaf(ww, (v).w, Sarr[(k)+3]);

__global__ __launch_bounds__(256) void k_attn(
    const float* __restrict__ af, float* __restrict__ wtS,
    const int* __restrict__ edge_start, const int* __restrict__ src_sorted,
    const float* __restrict__ dist_sorted, float* __restrict__ wsum) {
  int tid = threadIdx.x;
  int lane = tid & 63;
  int wv = tid >> 6;
  int h0 = 2 * wv, h1 = 2 * wv + 1;
  int g = lane >> 4;          // edge group 0..3
  int sub = lane & 15;        // dim group: dims [sub*16, sub*16+16)
  int b = blockIdx.x;

  int s0 = edge_start[b], e1 = edge_start[b + 1];   // issue early
  float* wtb = wtS + (size_t)b * 2560;
  const float* wr0 = wtb + h0 * 320;
  const float* wr1 = wtb + h1 * 320;

  float W0[16], W1[16], wd0[4], wd1[4];
#pragma unroll
  for (int j = 0; j < 4; ++j) {
    float4 t0 = *(const float4*)(wr0 + sub * 16 + 4 * j);
    float4 t1 = *(const float4*)(wr1 + sub * 16 + 4 * j);
    W0[4*j+0] = t0.x; W0[4*j+1] = t0.y; W0[4*j+2] = t0.z; W0[4*j+3] = t0.w;
    W1[4*j+0] = t1.x; W1[4*j+1] = t1.y; W1[4*j+2] = t1.z; W1[4*j+3] = t1.w;
  }
#pragma unroll
  for (int j = 0; j < 4; ++j) { wd0[j] = wr0[256 + sub + 16*j]; wd1[j] = wr1[256 + sub + 16*j]; }

  float cj[4];
#pragma unroll
  for (int j = 0; j < 4; ++j) cj[j] = (float)(sub + 16 * j) * DELTA;

  float l0 = 0.f, l1 = 0.f;
  float S0r[16] = {}, S1r[16] = {};
  float sd0[4] = {}, sd1[4] = {};

  if (s0 < e1) {
    int iaC = src_sorted[s0 + 8 + g];
    int iaD = src_sorted[s0 + 12 + g];
    float ddA = dist_sorted[s0 + g];
    float ddB = dist_sorted[s0 + 4 + g];
    float ddC = dist_sorted[s0 + 8 + g];
    float ddD = dist_sorted[s0 + 12 + g];
    int iaA = src_sorted[s0 + g];
    int iaB = src_sorted[s0 + 4 + g];
    const float4* rA = (const float4*)(af + (size_t)iaA * 256 + sub * 16);
    const float4* rB = (const float4*)(af + (size_t)iaB * 256 + sub * 16);
    float4 A0 = rA[0], A1 = rA[1], A2 = rA[2], A3 = rA[3];
    float4 B0 = rB[0], B1 = rB[1], B2 = rB[2], B3 = rB[3];

    for (int eb = s0; eb < e1; eb += 8) {
      int iaC2 = src_sorted[eb + 16 + g];
      float ddC2 = dist_sorted[eb + 16 + g];
      int iaD2 = src_sorted[eb + 20 + g];
      float ddD2 = dist_sorted[eb + 20 + g];
      const float4* rC = (const float4*)(af + (size_t)iaC * 256 + sub * 16);
      float4 C0 = rC[0], C1 = rC[1], C2 = rC[2], C3 = rC[3];

      float embA[4], embB[4];
#pragma unroll
      for (int j = 0; j < 4; ++j) {
        float da = ddA - cj[j]; embA[j] = __expf(GCOEFF * da * da);
        float db = ddB - cj[j]; embB[j] = __expf(GCOEFF * db * db);
      }
      float pA0 = 0.f, pA1 = 0.f, pB0 = 0.f, pB1 = 0.f;
      FMA4(pA0, A0, W0, 0);  FMA4(pA1, A0, W1, 0);
      FMA4(pB0, B0, W0, 0);  FMA4(pB1, B0, W1, 0);
      FMA4(pA0, A1, W0, 4);  FMA4(pA1, A1, W1, 4);
      FMA4(pB0, B1, W0, 4);  FMA4(pB1, B1, W1, 4);
      FMA4(pA0, A2, W0, 8);  FMA4(pA1, A2, W1, 8);
      FMA4(pB0, B2, W0, 8);  FMA4(pB1, B2, W1, 8);
      FMA4(pA0, A3, W0, 12); FMA4(pA1, A3, W1, 12);
      FMA4(pB0, B3, W0, 12); FMA4(pB1, B3, W1, 12);
#pragma unroll
      for (int j = 0; j < 4; ++j) {
        pA0 = fmaf(embA[j], wd0[j], pA0); pA1 = fmaf(embA[j], wd1[j], pA1);
        pB0 = fmaf(embB[j], wd0[j], pB0); pB1 = fmaf(embB[j], wd1[j], pB1);
      }
#pragma unroll
      for (int off = 8; off > 0; off >>= 1) {
        pA0 += __shfl_xor(pA0, off);
        pA1 += __shfl_xor(pA1, off);
        pB0 += __shfl_xor(pB0, off);
        pB1 += __shfl_xor(pB1, off);
      }
      float wA0 = __expf(pA0), wA1 = __expf(pA1);
      float wB0 = __expf(pB0), wB1 = __expf(pB1);
      if (eb + g >= e1)     { wA0 = 0.f; wA1 = 0.f; }
      if (eb + 4 + g >= e1) { wB0 = 0.f; wB1 = 0.f; }
      l0 += wA0 + wB0; l1 += wA1 + wB1;
#pragma unroll
      for (int j = 0; j < 4; ++j) {
        sd0[j] = fmaf(wA0, embA[j], sd0[j]); sd1[j] = fmaf(wA1, embA[j], sd1[j]);
        sd0[j] = fmaf(wB0, embB[j], sd0[j]); sd1[j] = fmaf(wB1, embB[j], sd1[j]);
      }

      ACC4(S0r, 0,  wA0, A0); ACC4(S1r, 0,  wA1, A0);
      ACC4(S0r, 4,  wA0, A1); ACC4(S1r, 4,  wA1, A1);
      ACC4(S0r, 8,  wA0, A2); ACC4(S1r, 8,  wA1, A2);
      ACC4(S0r, 12, wA0, A3); ACC4(S1r, 12, wA1, A3);

      const float4* rD = (const float4*)(af + (size_t)iaD * 256 + sub * 16);
      float4 D0 = rD[0], D1 = rD[1], D2 = rD[2], D3 = rD[3];

      ACC4(S0r, 0,  wB0, B0); ACC4(S1r, 0,  wB1, B0);
      ACC4(S0r, 4,  wB0, B1); ACC4(S1r, 4,  wB1, B1);
      ACC4(S0r, 8,  wB0, B2); ACC4(S1r, 8,  wB1, B2);
      ACC4(S0r, 12, wB0, B3); ACC4(S1r, 12, wB1, B3);

      A0 = C0; A1 = C1; A2 = C2; A3 = C3;
      B0 = D0; B1 = D1; B2 = D2; B3 = D3;
      ddA = ddC; ddB = ddD; ddC = ddC2; ddD = ddD2;
      iaC = iaC2; iaD = iaD2;
    }
  }

  // merge the 4 groups' partial sums
#pragma unroll
  for (int off = 16; off <= 32; off <<= 1) {
    l0 += __shfl_xor(l0, off);
    l1 += __shfl_xor(l1, off);
#pragma unroll
    for (int c = 0; c < 16; ++c) {
      S0r[c] += __shfl_xor(S0r[c], off);
      S1r[c] += __shfl_xor(S1r[c], off);
    }
#pragma unroll
    for (int j = 0; j < 4; ++j) {
      sd0[j] += __shfl_xor(sd0[j], off);
      sd1[j] += __shfl_xor(sd1[j], off);
    }
  }

  float inv0 = 1.0f / (l0 + 1e-16f), inv1 = 1.0f / (l1 + 1e-16f);
  if (g == 0) {
#pragma unroll
    for (int j = 0; j < 4; ++j) {
      float4 o0 = make_float4(S0r[4*j+0]*inv0, S0r[4*j+1]*inv0, S0r[4*j+2]*inv0, S0r[4*j+3]*inv0);
      float4 o1 = make_float4(S1r[4*j+0]*inv1, S1r[4*j+1]*inv1, S1r[4*j+2]*inv1, S1r[4*j+3]*inv1);
      *(float4*)(wtb + h0 * 320 + sub * 16 + 4 * j) = o0;
      *(float4*)(wtb + h1 * 320 + sub * 16 + 4 * j) = o1;
    }
#pragma unroll
    for (int j = 0; j < 4; ++j) {
      wtb[h0 * 320 + 256 + sub + 16 * j] = sd0[j] * inv0;
      wtb[h1 * 320 + 256 + sub + 16 * j] = sd1[j] * inv1;
    }
    if (sub == 0) {
      wsum[b * 8 + h0] = l0 * inv0;
      wsum[b * 8 + h1] = l1 * inv1;
    }
  }
}

// ---------------------------------------------------------------------------
// K8 v3: out_pre[b, h*32+c] = sum_i Sf[b,h*320+i]*Wv[i,h*32+c] + wsum*bv
// 256-row x 32-col tile, 8x4 microtile: per kk = 3 ds_read_b128 (~36cyc) vs
// 32 FMA (~64cyc) -> FMA-bound (old 4x4 was 2 reads per 16 FMA, read-limited).
// grid (40, 8). LDS 38KB -> 4 blocks/CU.
// ---------------------------------------------------------------------------
__global__ __launch_bounds__(256) void k_out_head(
    const float* __restrict__ Sf, const float* __restrict__ Wv,
    const float* __restrict__ bv, const float* __restrict__ wsum,
    float* __restrict__ out_pre) {
  __shared__ __align__(16) float As[32][264];   // Sf chunk transposed
  __shared__ __align__(16) float Bs[32][36];    // Wv chunk natural
  int tid = threadIdx.x;
  int b0 = blockIdx.x * 256;
  int h  = blockIdx.y;
  int tx = tid & 7, ty = tid >> 3;              // cols tx*4, rows ty*8
  float acc[8][4] = {};
  for (int k0 = 0; k0 < 320; k0 += 32) {
    {
      int row = b0 + tid;
      const float* sp = Sf + (size_t)row * 2560 + h * 320 + k0;
#pragma unroll
      for (int jj = 0; jj < 8; ++jj) {
        float4 v = make_float4(0.f, 0.f, 0.f, 0.f);
        if (row < B_BB) v = *(const float4*)(sp + 4 * jj);
        As[4*jj + 0][tid] = v.x; As[4*jj + 1][tid] = v.y;
        As[4*jj + 2][tid] = v.z; As[4*jj + 3][tid] = v.w;
      }
    }
    {
      int r = tid >> 3, c0 = (tid & 7) * 4;
      float4 v = *(const float4*)&Wv[(size_t)(k0 + r) * 256 + h * 32 + c0];
      *(float4*)&Bs[r][c0] = v;
    }
    __syncthreads();
#pragma unroll
    for (int kk = 0; kk < 32; ++kk) {
      float4 a0 = *(const float4*)&As[kk][ty * 8];
      float4 a1 = *(const float4*)&As[kk][ty * 8 + 4];
      float4 b4 = *(const float4*)&Bs[kk][tx * 4];
      float av[8] = {a0.x, a0.y, a0.z, a0.w, a1.x, a1.y, a1.z, a1.w};
      float bv4[4] = {b4.x, b4.y, b4.z, b4.w};
#pragma unroll
      for (int i = 0; i < 8; ++i)
#pragma unroll
        for (int j = 0; j < 4; ++j) acc[i][j] += av[i] * bv4[j];
    }
    __syncthreads();
  }
  float bvv[4];
#pragma unroll
  for (int j = 0; j < 4; ++j) bvv[j] = bv[h * 32 + tx * 4 + j];
#pragma unroll
  for (int i = 0; i < 8; ++i) {
    int row = b0 + ty * 8 + i;
    if (row < B_BB) {
      float ws = wsum[row * 8 + h];
      float4 o = make_float4(acc[i][0] + ws * bvv[0], acc[i][1] + ws * bvv[1],
                             acc[i][2] + ws * bvv[2], acc[i][3] + ws * bvv[3]);
      *(float4*)&out_pre[(size_t)row * 256 + h * 32 + tx * 4] = o;
    }
  }
}

// ---------------------------------------------------------------------------
extern "C" void kernel_launch(void* const* d_in, const int* in_sizes, int n_in,
                              void* d_out, int out_size, void* d_ws, size_t ws_size,
                              hipStream_t stream) {
  const float* af     = (const float*)d_in[0];
  const float* coords = (const float*)d_in[1];
  const float* Wq     = (const float*)d_in[2];
  const float* bq     = (const float*)d_in[3];
  const float* Wk     = (const float*)d_in[4];
  const float* bk     = (const float*)d_in[5];  (void)bk; // softmax-invariant, dropped
  const float* Wv     = (const float*)d_in[6];
  const float* bv     = (const float*)d_in[7];
  const float* Wo     = (const float*)d_in[8];
  const float* bo     = (const float*)d_in[9];
  const int* bb_vec   = (const int*)d_in[10];
  const int* src      = (const int*)d_in[11];
  const int* tgt      = (const int*)d_in[12];
  float* out = (float*)d_out;
  (void)in_sizes; (void)n_in; (void)out_size; (void)ws_size;

  char* ws = (char*)d_ws;
  size_t o = 0;
  auto alloc = [&](size_t bytes) { size_t r = o; o += (bytes + 255) & ~(size_t)255; return r; };
  int*   atom_off    = (int*)(ws + alloc((B_BB + 1) * 4));
  int*   edge_cnt    = (int*)(ws + alloc((size_t)B_BB * 4));
  int*   edge_start  = (int*)(ws + alloc((B_BB + 1) * 4));
  int*   cursor      = (int*)(ws + alloc((size_t)B_BB * 4));
  int*   src_sorted  = (int*)(ws + alloc((size_t)(E_EDGES + EPAD) * 4));
  float* dist_sorted = (float*)(ws + alloc((size_t)(E_EDGES + EPAD) * 4));
  float* bbF         = (float*)(ws + alloc((size_t)B_BB * 256 * 4));
  float* bb_pos      = (float*)(ws + alloc((size_t)B_BB * 4 * 4));
  float* q           = (float*)(ws + alloc((size_t)B_BB * 256 * 4));
  float* wtS         = (float*)(ws + alloc((size_t)B_BB * 2560 * 4)); // wt, then Sfull
  float* wsum        = (float*)(ws + alloc((size_t)B_BB * 8 * 4));
  float* out_pre     = (float*)(ws + alloc((size_t)B_BB * 256 * 4));

  k_offsets<<<(B_BB + 1 + 255) / 256, 256, 0, stream>>>(bb_vec, atom_off, edge_cnt);
  k_bb_centers<<<2560, 256, 0, stream>>>(af, coords, atom_off, bbF, bb_pos);
  k_hist<<<(E_EDGES + 255) / 256, 256, 0, stream>>>(tgt, edge_cnt);
  k_scan<<<1, 1024, 0, stream>>>(edge_cnt, edge_start, cursor, src_sorted, dist_sorted);
  k_fill<<<(E_EDGES + 255) / 256, 256, 0, stream>>>(src, tgt, coords, bb_pos, cursor,
                                                    src_sorted, dist_sorted);
  k_gemm256<<<dim3((B_BB + 63) / 64, 4), 256, 0, stream>>>(bbF, Wq, bq, q, B_BB);
  k_wt<<<dim3((B_BB + 127) / 128, 5, 8), 256, 0, stream>>>(q, Wk, wtS);
  k_attn<<<B_BB, 256, 0, stream>>>(af, wtS, edge_start, src_sorted, dist_sorted, wsum);
  k_out_head<<<dim3((B_BB + 255) / 256, 8), 256, 0, stream>>>(wtS, Wv, bv, wsum, out_pre);
  k_gemm256<<<dim3((B_BB + 63) / 64, 4), 256, 0, stream>>>(out_pre, Wo, bo, out, B_BB);
}

// Round 9
// 547.984 us; speedup vs baseline: 1.0386x; 1.0386x over previous
//
#include <hip/hip_runtime.h>
#include <math.h>

#define N_ATOMS 100000
#define B_BB    10000
#define E_EDGES 320000
#define D_DIM   256
#define NHEAD   8
#define NDIST   64
#define EPAD    128

#define DELTA   (10.0f/63.0f)
#define GCOEFF  (-0.5f/(DELTA*DELTA))
#define QKSCALE 0.17677669529663687f   /* 1/sqrt(32) */

// ---------------------------------------------------------------------------
// K0: per-bb atom offsets via binary search (bb_vec sorted); zero edge_cnt
// ---------------------------------------------------------------------------
__global__ void k_offsets(const int* __restrict__ bb_vec, int* __restrict__ atom_off,
                          int* __restrict__ edge_cnt) {
  int b = blockIdx.x * 256 + threadIdx.x;
  if (b <= B_BB) {
    int lo = 0, hi = N_ATOMS;
    while (lo < hi) { int mid = (lo + hi) >> 1; if (bb_vec[mid] < b) lo = mid + 1; else hi = mid; }
    atom_off[b] = lo;
  }
  if (b < B_BB) edge_cnt[b] = 0;
}

// ---------------------------------------------------------------------------
// K1: bb_center_feats (sum) and bb_center_pos (mean). Grid-stride over bbs.
// ---------------------------------------------------------------------------
__global__ __launch_bounds__(256) void k_bb_centers(
    const float* __restrict__ af, const float* __restrict__ coords,
    const int* __restrict__ atom_off, float* __restrict__ bbF, float* __restrict__ bb_pos) {
  int t = threadIdx.x;
  for (int b = blockIdx.x; b < B_BB; b += gridDim.x) {
    int s = atom_off[b], e = atom_off[b + 1];
    float acc = 0.f;
    for (int a = s; a < e; a++) acc += af[(size_t)a * D_DIM + t];
    bbF[(size_t)b * D_DIM + t] = acc;
    if (t < 3) {
      float c = 0.f;
      for (int a = s; a < e; a++) c += coords[(size_t)a * 3 + t];
      float cnt = (float)(e - s);
      bb_pos[b * 4 + t] = c / fmaxf(cnt, 1.0f);
    }
  }
}

// ---------------------------------------------------------------------------
// K2/K9 v3: C[M,256] = A[M,256] @ W[256,256] + bias. 64x64 tile, 4x4 microtile
// + register-staged double buffer, one barrier per K-chunk (R7 A/B: -10us).
// ---------------------------------------------------------------------------
__global__ __launch_bounds__(256) void k_gemm256(
    const float* __restrict__ A, const float* __restrict__ W,
    const float* __restrict__ bias, float* __restrict__ C, int M) {
  __shared__ __align__(16) float As[2][16][68];
  __shared__ __align__(16) float Ws[2][16][64];
  int tid = threadIdx.x;
  int tx = tid & 15, ty = tid >> 4;
  int row0 = blockIdx.x * 64, col0 = blockIdx.y * 64;
  int ar = tid >> 2, ac = (tid & 3) * 4;      // A stage: row ar, cols ac..ac+3
  int wr = tid >> 4, wc = (tid & 15) * 4;     // W stage: row wr, cols wc..wc+3
  int arow = row0 + ar;
  const float* Ap = A + (size_t)arow * 256 + ac;
  const float* Wp = W + (size_t)wr * 256 + col0 + wc;
  float acc[4][4] = {};
  {
    float4 va = make_float4(0.f, 0.f, 0.f, 0.f);
    if (arow < M) va = *(const float4*)Ap;
    As[0][ac + 0][ar] = va.x; As[0][ac + 1][ar] = va.y;
    As[0][ac + 2][ar] = va.z; As[0][ac + 3][ar] = va.w;
    *(float4*)&Ws[0][wr][wc] = *(const float4*)Wp;
  }
  __syncthreads();
  int cur = 0;
  for (int k0 = 0; k0 < 256; k0 += 16) {
    float4 va, vw;
    bool nxt = (k0 + 16) < 256;
    if (nxt) {
      va = make_float4(0.f, 0.f, 0.f, 0.f);
      if (arow < M) va = *(const float4*)(Ap + k0 + 16);
      vw = *(const float4*)(Wp + (size_t)(k0 + 16) * 256);
    }
#pragma unroll
    for (int kk = 0; kk < 16; kk++) {
      float4 a = *(const float4*)&As[cur][kk][ty * 4];
      float4 b = *(const float4*)&Ws[cur][kk][tx * 4];
      float av[4] = {a.x, a.y, a.z, a.w};
      float bv4[4] = {b.x, b.y, b.z, b.w};
#pragma unroll
      for (int i = 0; i < 4; i++)
#pragma unroll
        for (int j = 0; j < 4; j++) acc[i][j] += av[i] * bv4[j];
    }
    if (nxt) {
      As[cur ^ 1][ac + 0][ar] = va.x; As[cur ^ 1][ac + 1][ar] = va.y;
      As[cur ^ 1][ac + 2][ar] = va.z; As[cur ^ 1][ac + 3][ar] = va.w;
      *(float4*)&Ws[cur ^ 1][wr][wc] = vw;
      __syncthreads();
      cur ^= 1;
    }
  }
#pragma unroll
  for (int i = 0; i < 4; i++) {
    int row = row0 + ty * 4 + i;
    if (row < M) {
      int col = col0 + tx * 4;
      float4 r = make_float4(acc[i][0] + bias[col + 0], acc[i][1] + bias[col + 1],
                             acc[i][2] + bias[col + 2], acc[i][3] + bias[col + 3]);
      *(float4*)&C[(size_t)row * 256 + col] = r;
    }
  }
}

// ---------------------------------------------------------------------------
// K3: histogram of tgt
// ---------------------------------------------------------------------------
__global__ void k_hist(const int* __restrict__ tgt, int* __restrict__ edge_cnt) {
  int e = blockIdx.x * 256 + threadIdx.x;
  if (e < E_EDGES) atomicAdd(&edge_cnt[tgt[e]], 1);
}

// ---------------------------------------------------------------------------
// K4: exclusive scan of edge_cnt -> edge_start[B+1], cursor. Single block.
//     Also zero-fills the EPAD tail of src_sorted/dist_sorted.
// ---------------------------------------------------------------------------
__global__ __launch_bounds__(1024) void k_scan(
    const int* __restrict__ edge_cnt, int* __restrict__ edge_start, int* __restrict__ cursor,
    int* __restrict__ src_sorted, float* __restrict__ dist_sorted) {
  __shared__ int ssum[1024];
  int tid = threadIdx.x;
  int base = tid * 10;
  int v[10]; int s = 0;
#pragma unroll
  for (int k = 0; k < 10; k++) { int i = base + k; v[k] = (i < B_BB) ? edge_cnt[i] : 0; s += v[k]; }
  ssum[tid] = s;
  __syncthreads();
  for (int off = 1; off < 1024; off <<= 1) {
    int t = (tid >= off) ? ssum[tid - off] : 0;
    __syncthreads();
    ssum[tid] += t;
    __syncthreads();
  }
  int excl = ssum[tid] - s;
#pragma unroll
  for (int k = 0; k < 10; k++) {
    int i = base + k;
    if (i < B_BB) { edge_start[i] = excl; cursor[i] = excl; }
    excl += v[k];
  }
  if (tid == 1023) edge_start[B_BB] = E_EDGES;
  if (tid < EPAD) { src_sorted[E_EDGES + tid] = 0; dist_sorted[E_EDGES + tid] = 0.f; }
}

// ---------------------------------------------------------------------------
// K5: CSR fill: src_sorted / dist_sorted in tgt-grouped order
// ---------------------------------------------------------------------------
__global__ void k_fill(const int* __restrict__ src, const int* __restrict__ tgt,
                       const float* __restrict__ coords, const float* __restrict__ bb_pos,
                       int* __restrict__ cursor, int* __restrict__ src_sorted,
                       float* __restrict__ dist_sorted) {
  int e = blockIdx.x * 256 + threadIdx.x;
  if (e >= E_EDGES) return;
  int b = tgt[e], a = src[e];
  int pos = atomicAdd(&cursor[b], 1);
  float dx = coords[a * 3 + 0] - bb_pos[b * 4 + 0];
  float dy = coords[a * 3 + 1] - bb_pos[b * 4 + 1];
  float dz = coords[a * 3 + 2] - bb_pos[b * 4 + 2];
  src_sorted[pos] = a;
  dist_sorted[pos] = sqrtf(dx * dx + dy * dy + dz * dz);
}

// ---------------------------------------------------------------------------
// K6 v2: wt[b, h*320+i] = QKSCALE * sum_c q[b,h*32+c] * Wk[i, h*32+c]
// Register-blocked tile GEMM: 128 b-rows x 64 i-cols, K=32. grid (79,5,8).
// ---------------------------------------------------------------------------
__global__ __launch_bounds__(256) void k_wt(
    const float* __restrict__ q, const float* __restrict__ Wk, float* __restrict__ wt) {
  __shared__ __align__(16) float As[32][132];   // q transposed: As[c][row]
  __shared__ __align__(16) float Bs[32][68];    // Wk transposed: Bs[c][icol]
  int tid = threadIdx.x;
  int b0 = blockIdx.x * 128;
  int i0 = blockIdx.y * 64;
  int h  = blockIdx.z;
  {
    int r = tid >> 1, c0 = (tid & 1) * 16;
    int row = b0 + r;
    const float* qp = q + (size_t)row * 256 + h * 32 + c0;
#pragma unroll
    for (int jj = 0; jj < 4; ++jj) {
      float4 v = make_float4(0.f, 0.f, 0.f, 0.f);
      if (row < B_BB) v = *(const float4*)(qp + 4 * jj);
      As[c0 + 4*jj + 0][r] = v.x; As[c0 + 4*jj + 1][r] = v.y;
      As[c0 + 4*jj + 2][r] = v.z; As[c0 + 4*jj + 3][r] = v.w;
    }
  }
  {
    int r = tid >> 2, c0 = (tid & 3) * 8;
    const float* wp = Wk + (size_t)(i0 + r) * 256 + h * 32 + c0;
#pragma unroll
    for (int jj = 0; jj < 2; ++jj) {
      float4 v = *(const float4*)(wp + 4 * jj);
      Bs[c0 + 4*jj + 0][r] = v.x; Bs[c0 + 4*jj + 1][r] = v.y;
      Bs[c0 + 4*jj + 2][r] = v.z; Bs[c0 + 4*jj + 3][r] = v.w;
    }
  }
  __syncthreads();
  int tx = tid & 15, ty = tid >> 4;             // cols tx*4, rows ty*8
  float acc[8][4] = {};
#pragma unroll
  for (int kk = 0; kk < 32; ++kk) {
    float4 a0 = *(const float4*)&As[kk][ty * 8];
    float4 a1 = *(const float4*)&As[kk][ty * 8 + 4];
    float4 b4 = *(const float4*)&Bs[kk][tx * 4];
    float av[8] = {a0.x, a0.y, a0.z, a0.w, a1.x, a1.y, a1.z, a1.w};
    float bv4[4] = {b4.x, b4.y, b4.z, b4.w};
#pragma unroll
    for (int i = 0; i < 8; ++i)
#pragma unroll
      for (int j = 0; j < 4; ++j) acc[i][j] += av[i] * bv4[j];
  }
#pragma unroll
  for (int i = 0; i < 8; ++i) {
    int row = b0 + ty * 8 + i;
    if (row < B_BB) {
      float4 o = make_float4(acc[i][0] * QKSCALE, acc[i][1] * QKSCALE,
                             acc[i][2] * QKSCALE, acc[i][3] * QKSCALE);
      *(float4*)&wt[(size_t)row * 2560 + h * 320 + i0 + tx * 4] = o;
    }
  }
}

// ---------------------------------------------------------------------------
// K7 v10 (best: 157us, frozen): 8-edge iterations, two interleaved
// independent dot/shfl/exp chains; 1 bb per block.
// ---------------------------------------------------------------------------
#define FMA4(p, v, Wb, k) \
  p = fmaf((v).x, Wb[(k)], p);   p = fmaf((v).y, Wb[(k)+1], p); \
  p = fmaf((v).z, Wb[(k)+2], p); p = fmaf((v).w, Wb[(k)+3], p);

#define ACC4(Sarr, k, ww, v) \
  Sarr[(k)]   = fmaf(ww, (v).x, Sarr[(k)]);   Sarr[(k)+1] = fmaf(ww, (v).y, Sarr[(k)+1]); \
  Sarr[(k)+2] = fmaf(ww, (v).z, Sarr[(k)+2]); Sarr[(k)+3] = fmaf(ww, (v).w, Sarr[(k)+3]);

__global__ __launch_bounds__(256) void k_attn(
    const float* __restrict__ af, float* __restrict__ wtS,
    const int* __restrict__ edge_start, const int* __restrict__ src_sorted,
    const float* __restrict__ dist_sorted, float* __restrict__ wsum) {
  int tid = threadIdx.x;
  int lane = tid & 63;
  int wv = tid >> 6;
  int h0 = 2 * wv, h1 = 2 * wv + 1;
  int g = lane >> 4;          // edge group 0..3
  int sub = lane & 15;        // dim group: dims [sub*16, sub*16+16)
  int b = blockIdx.x;

  int s0 = edge_start[b], e1 = edge_start[b + 1];   // issue early
  float* wtb = wtS + (size_t)b * 2560;
  const float* wr0 = wtb + h0 * 320;
  const float* wr1 = wtb + h1 * 320;

  float W0[16], W1[16], wd0[4], wd1[4];
#pragma unroll
  for (int j = 0; j < 4; ++j) {
    float4 t0 = *(const float4*)(wr0 + sub * 16 + 4 * j);
    float4 t1 = *(const float4*)(wr1 + sub * 16 + 4 * j);
    W0[4*j+0] = t0.x; W0[4*j+1] = t0.y; W0[4*j+2] = t0.z; W0[4*j+3] = t0.w;
    W1[4*j+0] = t1.x; W1[4*j+1] = t1.y; W1[4*j+2] = t1.z; W1[4*j+3] = t1.w;
  }
#pragma unroll
  for (int j = 0; j < 4; ++j) { wd0[j] = wr0[256 + sub + 16*j]; wd1[j] = wr1[256 + sub + 16*j]; }

  float cj[4];
#pragma unroll
  for (int j = 0; j < 4; ++j) cj[j] = (float)(sub + 16 * j) * DELTA;

  float l0 = 0.f, l1 = 0.f;
  float S0r[16] = {}, S1r[16] = {};
  float sd0[4] = {}, sd1[4] = {};

  if (s0 < e1) {
    int iaC = src_sorted[s0 + 8 + g];
    int iaD = src_sorted[s0 + 12 + g];
    float ddA = dist_sorted[s0 + g];
    float ddB = dist_sorted[s0 + 4 + g];
    float ddC = dist_sorted[s0 + 8 + g];
    float ddD = dist_sorted[s0 + 12 + g];
    int iaA = src_sorted[s0 + g];
    int iaB = src_sorted[s0 + 4 + g];
    const float4* rA = (const float4*)(af + (size_t)iaA * 256 + sub * 16);
    const float4* rB = (const float4*)(af + (size_t)iaB * 256 + sub * 16);
    float4 A0 = rA[0], A1 = rA[1], A2 = rA[2], A3 = rA[3];
    float4 B0 = rB[0], B1 = rB[1], B2 = rB[2], B3 = rB[3];

    for (int eb = s0; eb < e1; eb += 8) {
      int iaC2 = src_sorted[eb + 16 + g];
      float ddC2 = dist_sorted[eb + 16 + g];
      int iaD2 = src_sorted[eb + 20 + g];
      float ddD2 = dist_sorted[eb + 20 + g];
      const float4* rC = (const float4*)(af + (size_t)iaC * 256 + sub * 16);
      float4 C0 = rC[0], C1 = rC[1], C2 = rC[2], C3 = rC[3];

      float embA[4], embB[4];
#pragma unroll
      for (int j = 0; j < 4; ++j) {
        float da = ddA - cj[j]; embA[j] = __expf(GCOEFF * da * da);
        float db = ddB - cj[j]; embB[j] = __expf(GCOEFF * db * db);
      }
      float pA0 = 0.f, pA1 = 0.f, pB0 = 0.f, pB1 = 0.f;
      FMA4(pA0, A0, W0, 0);  FMA4(pA1, A0, W1, 0);
      FMA4(pB0, B0, W0, 0);  FMA4(pB1, B0, W1, 0);
      FMA4(pA0, A1, W0, 4);  FMA4(pA1, A1, W1, 4);
      FMA4(pB0, B1, W0, 4);  FMA4(pB1, B1, W1, 4);
      FMA4(pA0, A2, W0, 8);  FMA4(pA1, A2, W1, 8);
      FMA4(pB0, B2, W0, 8);  FMA4(pB1, B2, W1, 8);
      FMA4(pA0, A3, W0, 12); FMA4(pA1, A3, W1, 12);
      FMA4(pB0, B3, W0, 12); FMA4(pB1, B3, W1, 12);
#pragma unroll
      for (int j = 0; j < 4; ++j) {
        pA0 = fmaf(embA[j], wd0[j], pA0); pA1 = fmaf(embA[j], wd1[j], pA1);
        pB0 = fmaf(embB[j], wd0[j], pB0); pB1 = fmaf(embB[j], wd1[j], pB1);
      }
#pragma unroll
      for (int off = 8; off > 0; off >>= 1) {
        pA0 += __shfl_xor(pA0, off);
        pA1 += __shfl_xor(pA1, off);
        pB0 += __shfl_xor(pB0, off);
        pB1 += __shfl_xor(pB1, off);
      }
      float wA0 = __expf(pA0), wA1 = __expf(pA1);
      float wB0 = __expf(pB0), wB1 = __expf(pB1);
      if (eb + g >= e1)     { wA0 = 0.f; wA1 = 0.f; }
      if (eb + 4 + g >= e1) { wB0 = 0.f; wB1 = 0.f; }
      l0 += wA0 + wB0; l1 += wA1 + wB1;
#pragma unroll
      for (int j = 0; j < 4; ++j) {
        sd0[j] = fmaf(wA0, embA[j], sd0[j]); sd1[j] = fmaf(wA1, embA[j], sd1[j]);
        sd0[j] = fmaf(wB0, embB[j], sd0[j]); sd1[j] = fmaf(wB1, embB[j], sd1[j]);
      }

      ACC4(S0r, 0,  wA0, A0); ACC4(S1r, 0,  wA1, A0);
      ACC4(S0r, 4,  wA0, A1); ACC4(S1r, 4,  wA1, A1);
      ACC4(S0r, 8,  wA0, A2); ACC4(S1r, 8,  wA1, A2);
      ACC4(S0r, 12, wA0, A3); ACC4(S1r, 12, wA1, A3);

      const float4* rD = (const float4*)(af + (size_t)iaD * 256 + sub * 16);
      float4 D0 = rD[0], D1 = rD[1], D2 = rD[2], D3 = rD[3];

      ACC4(S0r, 0,  wB0, B0); ACC4(S1r, 0,  wB1, B0);
      ACC4(S0r, 4,  wB0, B1); ACC4(S1r, 4,  wB1, B1);
      ACC4(S0r, 8,  wB0, B2); ACC4(S1r, 8,  wB1, B2);
      ACC4(S0r, 12, wB0, B3); ACC4(S1r, 12, wB1, B3);

      A0 = C0; A1 = C1; A2 = C2; A3 = C3;
      B0 = D0; B1 = D1; B2 = D2; B3 = D3;
      ddA = ddC; ddB = ddD; ddC = ddC2; ddD = ddD2;
      iaC = iaC2; iaD = iaD2;
    }
  }

  // merge the 4 groups' partial sums
#pragma unroll
  for (int off = 16; off <= 32; off <<= 1) {
    l0 += __shfl_xor(l0, off);
    l1 += __shfl_xor(l1, off);
#pragma unroll
    for (int c = 0; c < 16; ++c) {
      S0r[c] += __shfl_xor(S0r[c], off);
      S1r[c] += __shfl_xor(S1r[c], off);
    }
#pragma unroll
    for (int j = 0; j < 4; ++j) {
      sd0[j] += __shfl_xor(sd0[j], off);
      sd1[j] += __shfl_xor(sd1[j], off);
    }
  }

  float inv0 = 1.0f / (l0 + 1e-16f), inv1 = 1.0f / (l1 + 1e-16f);
  if (g == 0) {
#pragma unroll
    for (int j = 0; j < 4; ++j) {
      float4 o0 = make_float4(S0r[4*j+0]*inv0, S0r[4*j+1]*inv0, S0r[4*j+2]*inv0, S0r[4*j+3]*inv0);
      float4 o1 = make_float4(S1r[4*j+0]*inv1, S1r[4*j+1]*inv1, S1r[4*j+2]*inv1, S1r[4*j+3]*inv1);
      *(float4*)(wtb + h0 * 320 + sub * 16 + 4 * j) = o0;
      *(float4*)(wtb + h1 * 320 + sub * 16 + 4 * j) = o1;
    }
#pragma unroll
    for (int j = 0; j < 4; ++j) {
      wtb[h0 * 320 + 256 + sub + 16 * j] = sd0[j] * inv0;
      wtb[h1 * 320 + 256 + sub + 16 * j] = sd1[j] * inv1;
    }
    if (sub == 0) {
      wsum[b * 8 + h0] = l0 * inv0;
      wsum[b * 8 + h1] = l1 * inv1;
    }
  }
}

// ---------------------------------------------------------------------------
// K8 v4: v2's exact tiling (128 rows x 32 cols, 4x4 micro, grid (79,8)) +
// T14 async split: chunk k+1's global loads issue right after the barrier,
// a full compute phase before their ds_write. Single LDS buffer (keeps v2's
// 7 blocks/CU; full dbuf would halve it). v3 (256-row) reverted: its staging
// touched 64 lines/instr -> +21.6us (R8 A/B).
// ---------------------------------------------------------------------------
__global__ __launch_bounds__(256) void k_out_head(
    const float* __restrict__ Sf, const float* __restrict__ Wv,
    const float* __restrict__ bv, const float* __restrict__ wsum,
    float* __restrict__ out_pre) {
  __shared__ __align__(16) float As[32][132];   // Sf chunk transposed
  __shared__ __align__(16) float Bs[32][36];    // Wv chunk natural
  int tid = threadIdx.x;
  int b0 = blockIdx.x * 128;
  int h  = blockIdx.y;
  int tx = tid & 7, ty = tid >> 3;              // cols tx*4, rows ty*4
  int sr = tid >> 1, sc0 = (tid & 1) * 16;      // As stage: row sr, cols sc0..+15
  int wr = tid >> 3, wc0 = (tid & 7) * 4;       // Bs stage: row wr, cols wc0..+3
  int arow = b0 + sr;
  const float* sp = Sf + (size_t)arow * 2560 + h * 320 + sc0;
  const float* wp = Wv + (size_t)wr * 256 + h * 32 + wc0;
  bool aok = arow < B_BB;

  float4 sa0, sa1, sa2, sa3, sw;
  sa0 = sa1 = sa2 = sa3 = make_float4(0.f, 0.f, 0.f, 0.f);
  if (aok) {
    sa0 = *(const float4*)(sp);     sa1 = *(const float4*)(sp + 4);
    sa2 = *(const float4*)(sp + 8); sa3 = *(const float4*)(sp + 12);
  }
  sw = *(const float4*)(wp);

  float acc[4][4] = {};
  for (int k0 = 0; k0 < 320; k0 += 32) {
    // write staged chunk k0 to LDS (previous compute finished at loop-end barrier)
    As[sc0 + 0][sr] = sa0.x; As[sc0 + 1][sr] = sa0.y; As[sc0 + 2][sr] = sa0.z; As[sc0 + 3][sr] = sa0.w;
    As[sc0 + 4][sr] = sa1.x; As[sc0 + 5][sr] = sa1.y; As[sc0 + 6][sr] = sa1.z; As[sc0 + 7][sr] = sa1.w;
    As[sc0 + 8][sr] = sa2.x; As[sc0 + 9][sr] = sa2.y; As[sc0 +10][sr] = sa2.z; As[sc0 +11][sr] = sa2.w;
    As[sc0 +12][sr] = sa3.x; As[sc0 +13][sr] = sa3.y; As[sc0 +14][sr] = sa3.z; As[sc0 +15][sr] = sa3.w;
    *(float4*)&Bs[wr][wc0] = sw;
    __syncthreads();
    // issue chunk k0+32 loads now — latency hides under the compute below
    if (k0 + 32 < 320) {
      sa0 = sa1 = sa2 = sa3 = make_float4(0.f, 0.f, 0.f, 0.f);
      if (aok) {
        sa0 = *(const float4*)(sp + k0 + 32);      sa1 = *(const float4*)(sp + k0 + 36);
        sa2 = *(const float4*)(sp + k0 + 40);      sa3 = *(const float4*)(sp + k0 + 44);
      }
      sw = *(const float4*)(wp + (size_t)(k0 + 32) * 256);
    }
#pragma unroll
    for (int kk = 0; kk < 32; ++kk) {
      float4 a4 = *(const float4*)&As[kk][ty * 4];
      float4 b4 = *(const float4*)&Bs[kk][tx * 4];
      float av[4] = {a4.x, a4.y, a4.z, a4.w};
      float bv4[4] = {b4.x, b4.y, b4.z, b4.w};
#pragma unroll
      for (int i = 0; i < 4; ++i)
#pragma unroll
        for (int j = 0; j < 4; ++j) acc[i][j] += av[i] * bv4[j];
    }
    __syncthreads();
  }
  float bvv[4];
#pragma unroll
  for (int j = 0; j < 4; ++j) bvv[j] = bv[h * 32 + tx * 4 + j];
#pragma unroll
  for (int i = 0; i < 4; ++i) {
    int row = b0 + ty * 4 + i;
    if (row < B_BB) {
      float ws = wsum[row * 8 + h];
      float4 o = make_float4(acc[i][0] + ws * bvv[0], acc[i][1] + ws * bvv[1],
                             acc[i][2] + ws * bvv[2], acc[i][3] + ws * bvv[3]);
      *(float4*)&out_pre[(size_t)row * 256 + h * 32 + tx * 4] = o;
    }
  }
}

// ---------------------------------------------------------------------------
extern "C" void kernel_launch(void* const* d_in, const int* in_sizes, int n_in,
                              void* d_out, int out_size, void* d_ws, size_t ws_size,
                              hipStream_t stream) {
  const float* af     = (const float*)d_in[0];
  const float* coords = (const float*)d_in[1];
  const float* Wq     = (const float*)d_in[2];
  const float* bq     = (const float*)d_in[3];
  const float* Wk     = (const float*)d_in[4];
  const float* bk     = (const float*)d_in[5];  (void)bk; // softmax-invariant, dropped
  const float* Wv     = (const float*)d_in[6];
  const float* bv     = (const float*)d_in[7];
  const float* Wo     = (const float*)d_in[8];
  const float* bo     = (const float*)d_in[9];
  const int* bb_vec   = (const int*)d_in[10];
  const int* src      = (const int*)d_in[11];
  const int* tgt      = (const int*)d_in[12];
  float* out = (float*)d_out;
  (void)in_sizes; (void)n_in; (void)out_size; (void)ws_size;

  char* ws = (char*)d_ws;
  size_t o = 0;
  auto alloc = [&](size_t bytes) { size_t r = o; o += (bytes + 255) & ~(size_t)255; return r; };
  int*   atom_off    = (int*)(ws + alloc((B_BB + 1) * 4));
  int*   edge_cnt    = (int*)(ws + alloc((size_t)B_BB * 4));
  int*   edge_start  = (int*)(ws + alloc((B_BB + 1) * 4));
  int*   cursor      = (int*)(ws + alloc((size_t)B_BB * 4));
  int*   src_sorted  = (int*)(ws + alloc((size_t)(E_EDGES + EPAD) * 4));
  float* dist_sorted = (float*)(ws + alloc((size_t)(E_EDGES + EPAD) * 4));
  float* bbF         = (float*)(ws + alloc((size_t)B_BB * 256 * 4));
  float* bb_pos      = (float*)(ws + alloc((size_t)B_BB * 4 * 4));
  float* q           = (float*)(ws + alloc((size_t)B_BB * 256 * 4));
  float* wtS         = (float*)(ws + alloc((size_t)B_BB * 2560 * 4)); // wt, then Sfull
  float* wsum        = (float*)(ws + alloc((size_t)B_BB * 8 * 4));
  float* out_pre     = (float*)(ws + alloc((size_t)B_BB * 256 * 4));

  k_offsets<<<(B_BB + 1 + 255) / 256, 256, 0, stream>>>(bb_vec, atom_off, edge_cnt);
  k_bb_centers<<<2560, 256, 0, stream>>>(af, coords, atom_off, bbF, bb_pos);
  k_hist<<<(E_EDGES + 255) / 256, 256, 0, stream>>>(tgt, edge_cnt);
  k_scan<<<1, 1024, 0, stream>>>(edge_cnt, edge_start, cursor, src_sorted, dist_sorted);
  k_fill<<<(E_EDGES + 255) / 256, 256, 0, stream>>>(src, tgt, coords, bb_pos, cursor,
                                                    src_sorted, dist_sorted);
  k_gemm256<<<dim3((B_BB + 63) / 64, 4), 256, 0, stream>>>(bbF, Wq, bq, q, B_BB);
  k_wt<<<dim3((B_BB + 127) / 128, 5, 8), 256, 0, stream>>>(q, Wk, wtS);
  k_attn<<<B_BB, 256, 0, stream>>>(af, wtS, edge_start, src_sorted, dist_sorted, wsum);
  k_out_head<<<dim3((B_BB + 127) / 128, 8), 256, 0, stream>>>(wtS, Wv, bv, wsum, out_pre);
  k_gemm256<<<dim3((B_BB + 63) / 64, 4), 256, 0, stream>>>(out_pre, Wo, bo, out, B_BB);
}